// Round 8
// baseline (116.177 us; speedup 1.0000x reference)
//
#include <hip/hip_runtime.h>
#include <math.h>

#define NB 4096     // batch
#define ND 512      // dim

typedef __bf16 bf16x8 __attribute__((ext_vector_type(8)));
typedef unsigned short u16x8 __attribute__((ext_vector_type(8)));
typedef _Float16 f16x8 __attribute__((ext_vector_type(8)));
typedef _Float16 f16x4 __attribute__((ext_vector_type(4)));
typedef float f32x4 __attribute__((ext_vector_type(4)));

__device__ inline unsigned short f2bf(float f){
  unsigned u = __float_as_uint(f);
  u += 0x7FFFu + ((u >> 16) & 1u);      // round-to-nearest-even
  return (unsigned short)(u >> 16);
}

// async global->LDS, 16B per lane. LDS dest = wave-uniform base + lane*16.
__device__ inline void gl2lds16(const unsigned short* g, unsigned short* l){
  __builtin_amdgcn_global_load_lds(
      (const __attribute__((address_space(1))) unsigned int*)g,
      (__attribute__((address_space(3))) unsigned int*)l, 16, 0, 0);
}

// fused: feats fp32 -> bf16; block 0 packs labels->u8 (C=256) + zeroes counter
__global__ __launch_bounds__(256) void convert_init(const float* feats, unsigned short* fb,
                                                    const int* labels, unsigned char* lab8,
                                                    unsigned* counter){
  size_t idx = (size_t)blockIdx.x * 256 + threadIdx.x;  // group of 8 elements
  const float4* p = (const float4*)(feats + idx * 8);
  float4 x0 = p[0], x1 = p[1];
  u16x8 v;
  v[0]=f2bf(x0.x); v[1]=f2bf(x0.y); v[2]=f2bf(x0.z); v[3]=f2bf(x0.w);
  v[4]=f2bf(x1.x); v[5]=f2bf(x1.y); v[6]=f2bf(x1.z); v[7]=f2bf(x1.w);
  *(u16x8*)(fb + idx * 8) = v;

  if (blockIdx.x == 0){
    const int t = threadIdx.x;
    const int4* lp = (const int4*)(labels + t*16);
    int4 a = lp[0], b = lp[1], c = lp[2], d = lp[3];
    unsigned char pk[16] = {
      (unsigned char)a.x,(unsigned char)a.y,(unsigned char)a.z,(unsigned char)a.w,
      (unsigned char)b.x,(unsigned char)b.y,(unsigned char)b.z,(unsigned char)b.w,
      (unsigned char)c.x,(unsigned char)c.y,(unsigned char)c.z,(unsigned char)c.w,
      (unsigned char)d.x,(unsigned char)d.y,(unsigned char)d.z,(unsigned char)d.w };
    *(int4*)(lab8 + t*16) = *(const int4*)pk;
    if (t == 0) counter[0] = 0;
  }
}

// PASS 1: sim = F F^T (bf16 in, fp32 acc, fp16 out). 128x128 tile, 4 waves,
// 4x4 16x16x32-MFMA frags, BK=32. DOUBLE-BUFFERED prefetch staging: iter k+1's
// global_load_lds issued BEFORE iter k's compute, so the vmcnt drain at the
// single per-iter barrier covers loads that are already ~complete (vs R5's
// naked L2 latency on the critical path, 2 barriers/iter).
// Grid: 528 upper-triangle blocks; off-diag blocks store tile AND transpose
// (MFMA dot products are bitwise-commutative).
__global__ __launch_bounds__(256) void gemm_sim(const unsigned short* fb, _Float16* sim){
  __shared__ unsigned short As[2][128*32];   // 2 x 8 KB
  __shared__ unsigned short Bs[2][128*32];   // 2 x 8 KB

  // triangular decode: t -> (by, bx), bx >= by, 32 blocks/dim
  const int t  = blockIdx.x;
  const int by = (int)((65.0 - sqrt(4225.0 - 8.0*(double)t)) * 0.5);
  const int bx = by + t - (by*(65 - by))/2;

  const int tid  = threadIdx.x;
  const int lane = tid & 63;
  const int wave = tid >> 6;
  const int m0   = (wave >> 1) * 64;
  const int n0   = (wave & 1) * 64;
  const int quad = lane >> 4;
  const int l15  = lane & 15;

  // staging: wave w owns rows [w*32, +32) of A and B; lane l -> row l/4, col (l%4)*8
  const int srow = lane >> 2;
  const int scol = (lane & 3) * 8;
  const unsigned short* aseg = fb + (size_t)(by*128 + wave*32 + srow) * ND + scol;
  const unsigned short* bseg = fb + (size_t)(bx*128 + wave*32 + srow) * ND + scol;
  const int lb0 = (wave*32) * 32;        // LDS short-offset of wave's chunk
  const int lb1 = (wave*32 + 16) * 32;

  f32x4 acc[4][4];
#pragma unroll
  for (int i=0;i<4;++i)
#pragma unroll
    for (int j=0;j<4;++j) acc[i][j] = (f32x4){0.f,0.f,0.f,0.f};

  // prologue: stage k-tile 0 into buffer 0
  gl2lds16(aseg,         &As[0][lb0]);
  gl2lds16(aseg + 16*ND, &As[0][lb1]);
  gl2lds16(bseg,         &Bs[0][lb0]);
  gl2lds16(bseg + 16*ND, &Bs[0][lb1]);
  __syncthreads();

#pragma unroll
  for (int it = 0; it < 16; ++it){
    const int cur = it & 1, nxt = cur ^ 1;
    if (it < 15){                       // prefetch next k-tile FIRST
      const int k0 = (it + 1) * 32;
      gl2lds16(aseg + k0,         &As[nxt][lb0]);
      gl2lds16(aseg + k0 + 16*ND, &As[nxt][lb1]);
      gl2lds16(bseg + k0,         &Bs[nxt][lb0]);
      gl2lds16(bseg + k0 + 16*ND, &Bs[nxt][lb1]);
    }

    bf16x8 af[4], bfr[4];
#pragma unroll
    for (int s = 0; s < 4; ++s){
      af[s]  = __builtin_bit_cast(bf16x8, *(const u16x8*)&As[cur][(m0 + s*16 + l15)*32 + quad*8]);
      bfr[s] = __builtin_bit_cast(bf16x8, *(const u16x8*)&Bs[cur][(n0 + s*16 + l15)*32 + quad*8]);
    }
#pragma unroll
    for (int sm=0;sm<4;++sm)
#pragma unroll
      for (int sn=0;sn<4;++sn)
        acc[sm][sn] = __builtin_amdgcn_mfma_f32_16x16x32_bf16(af[sm], bfr[sn], acc[sm][sn], 0, 0, 0);

    __syncthreads();   // (a) prefetch into nxt complete, (b) cur reads done before overwrite
  }

  // store epilogue. C/D layout: col = lane&15, row = quad*4 + reg per 16x16 subtile.
#pragma unroll
  for (int sm=0;sm<4;++sm){
    const int R0 = by*128 + m0 + sm*16 + quad*4;   // 4 consecutive rows
#pragma unroll
    for (int sn=0;sn<4;++sn){
      const int C = bx*128 + n0 + sn*16 + l15;
      f16x4 h;
#pragma unroll
      for (int reg=0;reg<4;++reg) h[reg] = (_Float16)acc[sm][sn][reg];
#pragma unroll
      for (int reg=0;reg<4;++reg)
        sim[(size_t)(R0+reg)*NB + C] = h[reg];     // L2 merges to full lines
      if (bx != by)
        *(f16x4*)(sim + (size_t)C*NB + R0) = h;    // transpose mirror, 8B
    }
  }
}

// PASS 2: one row per WAVE, no per-element atomics. Wave loads its whole row
// (64 fp16/lane, 8 independent 16B loads), phase A butterfly (totals land in
// every lane -> wave-uniform thresholds free), phase B over same registers,
// LDS-reduce 4 wave losses, one plain store; done-counter + last-block final
// reduction (finalize kernel fused away).
__global__ __launch_bounds__(256) void row_stats(const _Float16* sim, const unsigned char* lab8,
                                                 float* blockLoss, unsigned* counter, float* out){
  __shared__ unsigned char slab[NB];   // 4 KB: all labels as bytes
  __shared__ float wloss[4];
  __shared__ unsigned sTicket;
  const int tid  = threadIdx.x;
  *(int4*)&slab[tid*16] = *(const int4*)&lab8[tid*16];
  __syncthreads();

  const int lane = tid & 63;
  const int wv   = tid >> 6;
  const int r    = blockIdx.x * 4 + wv;
  const int labR = (int)slab[r];                    // wave-uniform
  const _Float16* rowp = sim + (size_t)r * NB;

  // load whole row: chunk c covers cols c*512 + lane*8 .. +7
  f16x8 h[8];
  unsigned long long lb[8];
#pragma unroll
  for (int c=0;c<8;++c)
    h[c] = *(const f16x8*)(rowp + c*512 + lane*8);
#pragma unroll
  for (int c=0;c<8;++c)
    lb[c] = *(const unsigned long long*)&slab[c*512 + lane*8];

  // phase A: sum, min_pos (same & <1-eps), max_neg (diff)
  float s = 0.f, mp = 3.0e38f, mn = -3.0e38f;
#pragma unroll
  for (int c=0;c<8;++c){
    const unsigned long long L = lb[c];
#pragma unroll
    for (int j=0;j<8;++j){
      const float x = (float)h[c][j];
      const int lj = (int)((L >> (8*j)) & 0xffULL);
      s += x;
      if (lj == labR){ if (x < 0.99999f) mp = fminf(mp, x); }
      else           { mn = fmaxf(mn, x); }
    }
  }
#pragma unroll
  for (int o=1;o<64;o<<=1){
    s  += __shfl_xor(s, o, 64);
    mp  = fminf(mp, __shfl_xor(mp, o, 64));
    mn  = fmaxf(mn, __shfl_xor(mn, o, 64));
  }
  const bool hp = (mp < 1.0e38f), hn = (mn > -1.0e38f);
  const float mpr = hp ? mp : 1.0e9f;               // BIG like reference
  const float mnr = hn ? mn : -1.0e9f;
  const float mean_ = (s * (1.0f/(float)NB) + 0.5f*(mpr+mnr)) * 0.5f;
  const float tpp = mnr + 0.1f;                     // pp: x < max_neg + MARGIN
  const float tnm = mpr - 0.1f;                     // nm: x > min_pos - MARGIN

  // phase B: sigma, fp, fn from the same registers
  float sg = 0.f, fps = 0.f, fns = 0.f;
#pragma unroll
  for (int c=0;c<8;++c){
    const unsigned long long L = lb[c];
#pragma unroll
    for (int j=0;j<8;++j){
      const float x = (float)h[c][j];
      const int lj = (int)((L >> (8*j)) & 0xffULL);
      if (lj != labR){
        const float d = x - mean_; sg += d*d;
        if (x > tnm) fns += __expf((x - 0.5f) * 40.0f);
      } else if (x < 0.99999f && x < tpp){
        fps += __expf(-(x - 0.5f) * 2.0f);
      }
    }
  }
#pragma unroll
  for (int o=1;o<64;o<<=1){
    sg  += __shfl_xor(sg,  o, 64);
    fps += __shfl_xor(fps, o, 64);
    fns += __shfl_xor(fns, o, 64);
  }

  if (lane == 0){
    wloss[wv] = (hp && hn && fps > 0.f && fns > 0.f)
                ? (logf(1.f + fps) + logf(1.f + fns) + 0.1f * sg) : 0.f;
  }
  __syncthreads();
  if (tid == 0){
    blockLoss[blockIdx.x] = wloss[0] + wloss[1] + wloss[2] + wloss[3];
    __threadfence();                       // publish blockLoss before ticket
    sTicket = atomicAdd(counter, 1);       // device-scope RMW
  }
  __syncthreads();

  if (sTicket == (unsigned)(gridDim.x - 1)){   // last block: final reduce
    __threadfence();                            // order after ticket observation
    float l = 0.f;
    for (int i = tid; i < NB/4; i += 256) l += blockLoss[i];
#pragma unroll
    for (int o=1;o<64;o<<=1) l += __shfl_xor(l, o, 64);
    if (lane == 0) wloss[wv] = l;
    __syncthreads();
    if (tid == 0)
      out[0] = (wloss[0] + wloss[1] + wloss[2] + wloss[3]) * (1.0f/(float)NB);
  }
}

extern "C" void kernel_launch(void* const* d_in, const int* in_sizes, int n_in,
                              void* d_out, int out_size, void* d_ws, size_t ws_size,
                              hipStream_t stream) {
  (void)in_sizes; (void)n_in; (void)out_size; (void)ws_size;
  const float* feats  = (const float*)d_in[0];
  const int*   labels = (const int*)d_in[1];
  float* out = (float*)d_out;

  // ws layout: sim fp16 (32MB) | fb bf16 (4MB) | lab8 (4KB) | blockLoss (4KB) | counter
  _Float16* sim       = (_Float16*)d_ws;
  unsigned short* fb  = (unsigned short*)(sim + (size_t)NB*NB);
  unsigned char* lab8 = (unsigned char*)(fb + (size_t)NB*ND);
  float* blockLoss    = (float*)(lab8 + NB);
  unsigned* counter   = (unsigned*)(blockLoss + NB/4);

  convert_init<<<dim3((NB*ND/8)/256), dim3(256), 0, stream>>>(feats, fb, labels, lab8, counter);

  gemm_sim<<<dim3(528), dim3(256), 0, stream>>>(fb, sim);

  row_stats<<<dim3(NB/4), dim3(256), 0, stream>>>(sim, lab8, blockLoss, counter, out);
}

// Round 10
// 107.768 us; speedup vs baseline: 1.0780x; 1.0780x over previous
//
#include <hip/hip_runtime.h>
#include <math.h>

#define NB 4096     // batch
#define ND 512      // dim
#define HK 256      // half-K
#define PSTR 520    // shorts per LDS row-pair: 2*256 data + 8 pad (1040 B)

typedef __bf16 bf16x8 __attribute__((ext_vector_type(8)));
typedef unsigned short u16x8 __attribute__((ext_vector_type(8)));
typedef _Float16 f16x8 __attribute__((ext_vector_type(8)));
typedef _Float16 f16x4 __attribute__((ext_vector_type(4)));
typedef float f32x4 __attribute__((ext_vector_type(4)));

__device__ inline unsigned short f2bf(float f){
  unsigned u = __float_as_uint(f);
  u += 0x7FFFu + ((u >> 16) & 1u);      // round-to-nearest-even
  return (unsigned short)(u >> 16);
}

// async global->LDS: PER-LANE global address, LDS dest = uniform base + lane*16.
__device__ inline void gl2lds16(const unsigned short* g, unsigned short* l){
  __builtin_amdgcn_global_load_lds(
      (const __attribute__((address_space(1))) unsigned int*)g,
      (__attribute__((address_space(3))) unsigned int*)l, 16, 0, 0);
}

// feats fp32 -> bf16 in HALF-SPLIT layout: fb[h][row][c] = feats[row][h*256+c]
// so 2 consecutive same-half rows are 1 KB contiguous (one gl2lds16 wave-call).
// Block 0 also packs labels->u8 (C=256 fits a byte).
__global__ __launch_bounds__(256) void convert_init(const float* feats, unsigned short* fb,
                                                    const int* labels, unsigned char* lab8){
  size_t idx = (size_t)blockIdx.x * 256 + threadIdx.x;  // group of 8 elements
  const float4* p = (const float4*)(feats + idx * 8);
  float4 x0 = p[0], x1 = p[1];
  u16x8 v;
  v[0]=f2bf(x0.x); v[1]=f2bf(x0.y); v[2]=f2bf(x0.z); v[3]=f2bf(x0.w);
  v[4]=f2bf(x1.x); v[5]=f2bf(x1.y); v[6]=f2bf(x1.z); v[7]=f2bf(x1.w);
  const int row  = (int)(idx >> 6);          // 64 groups of 8 per 512-col row
  const int col8 = (int)(idx & 63) * 8;
  const int h    = col8 >> 8;                // which K-half
  const int c    = col8 & 255;
  *(u16x8*)(fb + (size_t)h*(NB*HK) + (size_t)row*HK + c) = v;

  if (blockIdx.x == 0){
    const int t = threadIdx.x;
    const int4* lp = (const int4*)(labels + t*16);
    int4 a = lp[0], b = lp[1], c2 = lp[2], d = lp[3];
    unsigned char pk[16] = {
      (unsigned char)a.x,(unsigned char)a.y,(unsigned char)a.z,(unsigned char)a.w,
      (unsigned char)b.x,(unsigned char)b.y,(unsigned char)b.z,(unsigned char)b.w,
      (unsigned char)c2.x,(unsigned char)c2.y,(unsigned char)c2.z,(unsigned char)c2.w,
      (unsigned char)d.x,(unsigned char)d.y,(unsigned char)d.z,(unsigned char)d.w };
    *(int4*)(lab8 + t*16) = *(const int4*)pk;
  }
}

// PASS 1: sim = F F^T. 64x64 tiles, whole K-half of BOTH tiles resident in LDS
// -> 2 stage/compute phases per block (4 barriers total vs 32 in the BK=32
// loop). Staging = 16-deep async gl2lds16 queue per wave -> L2 latency
// amortized; kernel is L2-BW-bound, not barrier-latency-bound.
// Pair-padded LDS (1040 B/pair): b128 frag reads hit each bank exactly
// 8x/wave (phase minimum); pads fall BETWEEN 1 KB staging calls.
// Grid: 2080 upper-triangle blocks; off-diag store tile AND transpose
// (MFMA dot products bitwise-commutative -> overlap writes identical).
__global__ __launch_bounds__(256) void gemm_sim(const unsigned short* fb, _Float16* sim){
  __shared__ unsigned short As[32*PSTR];   // 32 row-pairs, 33.3 KB
  __shared__ unsigned short Bs[32*PSTR];

  // triangular decode over 64 tile-rows: S(by)=by*(129-by)/2, exact boundaries
  const int t  = blockIdx.x;
  const int by = (int)((129.0 - sqrt(16641.0 - 8.0*(double)t)) * 0.5);
  const int bx = by + (t - (by*(129 - by))/2);

  const int tid  = threadIdx.x;
  const int lane = tid & 63;
  const int wave = tid >> 6;
  const int m0   = (wave >> 1) * 32;   // wave's 32-row half of the 64-row tile
  const int n0   = (wave & 1) * 32;    // wave's 32-col half
  const int quad = lane >> 4;
  const int l15  = lane & 15;
  const int lsh  = lane * 8;           // per-lane staging offset (shorts) = lane*16 B
                                       // (R9 BUG: this term was missing -> all lanes
                                       //  fetched the same 16 B; LDS tile was garbage)

  // per-lane LDS frag offsets (shorts): row r lives at (r>>1)*PSTR + (r&1)*HK
  int aoff[2], boff[2];
#pragma unroll
  for (int s=0;s<2;++s){
    const int rA = m0 + s*16 + l15;
    const int rB = n0 + s*16 + l15;
    aoff[s] = (rA>>1)*PSTR + (rA&1)*HK + quad*8;
    boff[s] = (rB>>1)*PSTR + (rB&1)*HK + quad*8;
  }

  f32x4 acc[2][2];
#pragma unroll
  for (int i=0;i<2;++i)
#pragma unroll
    for (int j=0;j<2;++j) acc[i][j] = (f32x4){0.f,0.f,0.f,0.f};

  for (int ph = 0; ph < 2; ++ph){
    if (ph) __syncthreads();             // prior phase's LDS reads done
    const unsigned short* fbh = fb + (size_t)ph * (NB*HK);
    // stage whole K-half of A and B tiles: wave w -> row-pairs [8w, 8w+8)
#pragma unroll
    for (int i = 0; i < 8; ++i){
      const int p = wave*8 + i;
      gl2lds16(fbh + (size_t)(by*64 + 2*p)*HK + lsh, &As[p*PSTR]);
      gl2lds16(fbh + (size_t)(bx*64 + 2*p)*HK + lsh, &Bs[p*PSTR]);
    }
    __syncthreads();                     // staging (16 async calls/wave) drained

    // barrier-free compute: 8 k-steps over the resident K-half
#pragma unroll
    for (int kk = 0; kk < 8; ++kk){
      bf16x8 af[2], bf[2];
#pragma unroll
      for (int s=0;s<2;++s){
        af[s] = __builtin_bit_cast(bf16x8, *(const u16x8*)&As[aoff[s] + kk*32]);
        bf[s] = __builtin_bit_cast(bf16x8, *(const u16x8*)&Bs[boff[s] + kk*32]);
      }
#pragma unroll
      for (int sm=0;sm<2;++sm)
#pragma unroll
        for (int sn=0;sn<2;++sn)
          acc[sm][sn] = __builtin_amdgcn_mfma_f32_16x16x32_bf16(af[sm], bf[sn], acc[sm][sn], 0, 0, 0);
    }
  }

  // store epilogue. C/D layout: col = lane&15, row = quad*4 + reg per 16x16 subtile.
#pragma unroll
  for (int sm=0;sm<2;++sm){
    const int R0 = by*64 + m0 + sm*16 + quad*4;   // 4 consecutive rows
#pragma unroll
    for (int sn=0;sn<2;++sn){
      const int C = bx*64 + n0 + sn*16 + l15;
      f16x4 h;
#pragma unroll
      for (int reg=0;reg<4;++reg) h[reg] = (_Float16)acc[sm][sn][reg];
#pragma unroll
      for (int reg=0;reg<4;++reg)
        sim[(size_t)(R0+reg)*NB + C] = h[reg];     // L2 merges to full lines
      if (bx != by)
        *(f16x4*)(sim + (size_t)C*NB + R0) = h;    // transpose mirror, 8B
    }
  }
}

// PASS 2 (R5-proven): one row per WAVE, no atomics. 8 independent 16B loads,
// phase A butterfly (totals in every lane -> uniform thresholds free),
// phase B over same registers, LDS-reduce 4 wave losses, one plain store.
__global__ __launch_bounds__(256) void row_stats(const _Float16* sim, const unsigned char* lab8,
                                                 float* blockLoss){
  __shared__ unsigned char slab[NB];   // 4 KB: all labels as bytes
  __shared__ float wloss[4];
  const int tid  = threadIdx.x;
  *(int4*)&slab[tid*16] = *(const int4*)&lab8[tid*16];
  __syncthreads();

  const int lane = tid & 63;
  const int wv   = tid >> 6;
  const int r    = blockIdx.x * 4 + wv;
  const int labR = (int)slab[r];                    // wave-uniform
  const _Float16* rowp = sim + (size_t)r * NB;

  f16x8 h[8];
  unsigned long long lb[8];
#pragma unroll
  for (int c=0;c<8;++c)
    h[c] = *(const f16x8*)(rowp + c*512 + lane*8);
#pragma unroll
  for (int c=0;c<8;++c)
    lb[c] = *(const unsigned long long*)&slab[c*512 + lane*8];

  // phase A: sum, min_pos (same & <1-eps), max_neg (diff)
  float s = 0.f, mp = 3.0e38f, mn = -3.0e38f;
#pragma unroll
  for (int c=0;c<8;++c){
    const unsigned long long L = lb[c];
#pragma unroll
    for (int j=0;j<8;++j){
      const float x = (float)h[c][j];
      const int lj = (int)((L >> (8*j)) & 0xffULL);
      s += x;
      if (lj == labR){ if (x < 0.99999f) mp = fminf(mp, x); }
      else           { mn = fmaxf(mn, x); }
    }
  }
#pragma unroll
  for (int o=1;o<64;o<<=1){
    s  += __shfl_xor(s, o, 64);
    mp  = fminf(mp, __shfl_xor(mp, o, 64));
    mn  = fmaxf(mn, __shfl_xor(mn, o, 64));
  }
  const bool hp = (mp < 1.0e38f), hn = (mn > -1.0e38f);
  const float mpr = hp ? mp : 1.0e9f;               // BIG like reference
  const float mnr = hn ? mn : -1.0e9f;
  const float mean_ = (s * (1.0f/(float)NB) + 0.5f*(mpr+mnr)) * 0.5f;
  const float tpp = mnr + 0.1f;                     // pp: x < max_neg + MARGIN
  const float tnm = mpr - 0.1f;                     // nm: x > min_pos - MARGIN

  // phase B: sigma, fp, fn from the same registers
  float sg = 0.f, fps = 0.f, fns = 0.f;
#pragma unroll
  for (int c=0;c<8;++c){
    const unsigned long long L = lb[c];
#pragma unroll
    for (int j=0;j<8;++j){
      const float x = (float)h[c][j];
      const int lj = (int)((L >> (8*j)) & 0xffULL);
      if (lj != labR){
        const float d = x - mean_; sg += d*d;
        if (x > tnm) fns += __expf((x - 0.5f) * 40.0f);
      } else if (x < 0.99999f && x < tpp){
        fps += __expf(-(x - 0.5f) * 2.0f);
      }
    }
  }
#pragma unroll
  for (int o=1;o<64;o<<=1){
    sg  += __shfl_xor(sg,  o, 64);
    fps += __shfl_xor(fps, o, 64);
    fns += __shfl_xor(fns, o, 64);
  }

  if (lane == 0){
    wloss[wv] = (hp && hn && fps > 0.f && fns > 0.f)
                ? (logf(1.f + fps) + logf(1.f + fns) + 0.1f * sg) : 0.f;
  }
  __syncthreads();
  if (tid == 0)
    blockLoss[blockIdx.x] = wloss[0] + wloss[1] + wloss[2] + wloss[3];
}

__global__ __launch_bounds__(1024) void finalize(const float* blockLoss, float* out){
  const int tid = threadIdx.x;
  float l = blockLoss[tid];          // exactly NB/4 == 1024 entries
#pragma unroll
  for (int o=1;o<64;o<<=1) l += __shfl_xor(l, o, 64);
  __shared__ float red[16];
  if ((tid & 63) == 0) red[tid >> 6] = l;
  __syncthreads();
  if (tid == 0){
    float t = 0.f;
#pragma unroll
    for (int i=0;i<16;++i) t += red[i];
    out[0] = t * (1.0f/(float)NB);
  }
}

extern "C" void kernel_launch(void* const* d_in, const int* in_sizes, int n_in,
                              void* d_out, int out_size, void* d_ws, size_t ws_size,
                              hipStream_t stream) {
  (void)in_sizes; (void)n_in; (void)out_size; (void)ws_size;
  const float* feats  = (const float*)d_in[0];
  const int*   labels = (const int*)d_in[1];
  float* out = (float*)d_out;

  // ws layout: sim fp16 (32MB) | fb bf16 half-split (4MB) | lab8 (4KB) | blockLoss (4KB)
  _Float16* sim       = (_Float16*)d_ws;
  unsigned short* fb  = (unsigned short*)(sim + (size_t)NB*NB);
  unsigned char* lab8 = (unsigned char*)(fb + (size_t)NB*ND);
  float* blockLoss    = (float*)(lab8 + NB);

  convert_init<<<dim3((NB*ND/8)/256), dim3(256), 0, stream>>>(feats, fb, labels, lab8);

  gemm_sim<<<dim3(2080), dim3(256), 0, stream>>>(fb, sim);

  row_stats<<<dim3(NB/4), dim3(256), 0, stream>>>(sim, lab8, blockLoss);

  finalize<<<dim3(1), dim3(1024), 0, stream>>>(blockLoss, out);
}